// Round 10
// baseline (171.601 us; speedup 1.0000x reference)
//
#include <hip/hip_runtime.h>
#include <hip/hip_bf16.h>

#define K 16
#define Bn 1024
#define Tn 512
#define START_ID 14
#define STOP_ID 15
#define LN2 0.69314718055994530942f
#define NCH 8          // chunks per sequence (one block = one sequence)
#define CL 64          // chunk length == wave size; threadIdx.x == t

typedef float f32x4 __attribute__((ext_vector_type(4)));
typedef short s16x4 __attribute__((ext_vector_type(4)));

// f32x4 -> bf16x4 in 6 VALU (round-half-up +0x8000, hi16 via v_perm_b32)
static __device__ __forceinline__ s16x4 pack_bf16x4(float a, float b, float c, float d) {
    unsigned ua = __float_as_uint(a) + 0x8000u;
    unsigned ub = __float_as_uint(b) + 0x8000u;
    unsigned uc = __float_as_uint(c) + 0x8000u;
    unsigned ud = __float_as_uint(d) + 0x8000u;
    union { unsigned u[2]; s16x4 v; } un;
    un.u[0] = __builtin_amdgcn_perm(ub, ua, 0x07060302);
    un.u[1] = __builtin_amdgcn_perm(ud, uc, 0x07060302);
    return un.v;
}

// ---------------------------------------------------------------------------
// BYTE-IDENTICAL to the R8 kernel (which has a measured 2-launch total of
// 124.1 us). DO NOT TOUCH: this round is a controlled N=4 measurement;
// T4 - T2 = 2*(X+g) pins the true per-launch kernel cost with all harness
// overhead (fill/restore/graph) cancelling.
// ---------------------------------------------------------------------------
__global__ __launch_bounds__(512, 8) void crf_all(
    const float* __restrict__ h, const int* __restrict__ y,
    const float* __restrict__ trans, float* __restrict__ res)
{
    __shared__ float Pl[NCH][16][16];   // [chunk][row][col]
    __shared__ float El[NCH][16];       // per-column exponent sums
    __shared__ float Gl[NCH];           // per-wave gold partials

    int tid  = threadIdx.x;             // == t
    int lane = tid & 63;
    int c    = tid >> 6;                // wave id == chunk id
    int b    = blockIdx.x;
    int s = lane & 15, q = lane >> 4;

    const int* yseq = y + (size_t)b * Tn;
    int yt = yseq[tid];
    unsigned long long bal = __ballot(yt != 0);
    int nv = __popcll(bal);             // valid steps in this chunk (prefix)

    // ---- gold: one (b,t) per thread; also pre-warms L2 ----
    const float* hseq = h + ((size_t)b * Tn) * K;
    float g = 0.f;
    if (yt != 0) {
        int yp = (tid == 0) ? START_ID : yseq[tid - 1];
        g = hseq[(size_t)tid * K + yt] + trans[yt * K + yp];
        bool last = (tid == Tn - 1) || (yseq[tid + 1] == 0);
        if (last) g += trans[STOP_ID * K + yt];
    }
#pragma unroll
    for (int off = 32; off; off >>= 1) g += __shfl_xor(g, off, 64);
    if (lane == 0) Gl[c] = g;

    // ---- chain ----
    float E0[4];
#pragma unroll
    for (int r = 0; r < 4; ++r)
        E0[r] = __expf(trans[s * K + 4 * q + r]);   // exp(-10000) -> 0

    f32x4 P;
    s16x4 bfrag;
#pragma unroll
    for (int r = 0; r < 4; ++r) {
        P[r] = (4 * q + r == s) ? 1.0f : 0.0f;
        ((short*)&bfrag)[r] = (4 * q + r == s) ? (short)0x3F80 : (short)0;
    }

    int esum = 0, pend = 0;
    const float* hcs = hseq + (size_t)c * CL * K + s;

    float hcur[8], hnxt[8];
#pragma unroll
    for (int r = 0; r < 8; ++r) hcur[r] = hcs[(size_t)r * K];

    for (int sb = 0; sb < CL / 8; ++sb) {
        int base = sb * 8;
        if (base >= nv) break;                 // wave-uniform
        int n = nv - base; if (n > 8) n = 8;

        esum += pend;
        float sc = __uint_as_float((unsigned)(127 - pend) << 23); // exact 2^-pend
        pend = 0;
        P[0] *= sc; P[1] *= sc; P[2] *= sc; P[3] *= sc;
        bfrag = pack_bf16x4(P[0], P[1], P[2], P[3]);

        float es[8];
#pragma unroll
        for (int r = 0; r < 8; ++r) es[r] = __expf(hcur[r]);
#pragma unroll
        for (int r = 0; r < 8; ++r) {          // depth-1 prefetch (clamped)
            int tt = base + 8 + r; tt = tt > CL - 1 ? CL - 1 : tt;
            hnxt[r] = hcs[(size_t)tt * K];
        }
#pragma unroll
        for (int r = 0; r < 8; ++r) {
            if (r >= n) break;                 // wave-uniform
            s16x4 afrag = pack_bf16x4(es[r] * E0[0], es[r] * E0[1],
                                      es[r] * E0[2], es[r] * E0[3]);
            f32x4 C = __builtin_amdgcn_mfma_f32_16x16x16bf16_1k(
                afrag, bfrag, (f32x4){0.f, 0.f, 0.f, 0.f}, 0, 0, 0);
            if (r == 3) {                      // per-column max -> pending 2^e
                float m4 = fmaxf(fmaxf(C[0], C[1]), fmaxf(C[2], C[3]));
                m4 = fmaxf(m4, __shfl_xor(m4, 16, 64));
                m4 = fmaxf(m4, __shfl_xor(m4, 32, 64));
                int e = (int)(__float_as_uint(m4) >> 23) - 127;
                pend = e < -126 ? -126 : (e > 126 ? 126 : e);
            }
            bfrag = pack_bf16x4(C[0], C[1], C[2], C[3]);
            P = C;
        }
#pragma unroll
        for (int r = 0; r < 8; ++r) hcur[r] = hnxt[r];
    }

    // publish chunk result (column s, rows 4q+r)
#pragma unroll
    for (int r = 0; r < 4; ++r)
        Pl[c][4 * q + r][s] = P[r];
    if (q == 0) El[c][s] = (float)esum;
    __syncthreads();

    // ---- combine (wave 0): alpha = e_START; alpha' = P~ * ldexp(w) ----
    if (c == 0) {
        int j = s;
        float ap[4];
#pragma unroll
        for (int r = 0; r < 4; ++r) ap[r] = (4 * q + r == START_ID) ? 1.0f : 0.0f;
        float ls = 0.f;

#pragma unroll
        for (int cc = 0; cc < NCH; ++cc) {
            f32x4 Pr  = *(const f32x4*)&Pl[cc][j][4 * q];
            f32x4 Erv = *(const f32x4*)&El[cc][4 * q];
            float me = fmaxf(fmaxf(Erv[0], Erv[1]), fmaxf(Erv[2], Erv[3]));
            me = fmaxf(me, __shfl_xor(me, 16, 64));
            me = fmaxf(me, __shfl_xor(me, 32, 64));
            float w0 = ldexpf(ap[0], (int)(Erv[0] - me));
            float w1 = ldexpf(ap[1], (int)(Erv[1] - me));
            float w2 = ldexpf(ap[2], (int)(Erv[2] - me));
            float w3 = ldexpf(ap[3], (int)(Erv[3] - me));
            float acc = Pr[0]*w0 + Pr[1]*w1 + Pr[2]*w2 + Pr[3]*w3;
            acc += __shfl_xor(acc, 16, 64);
            acc += __shfl_xor(acc, 32, 64);    // alpha'[j] at every lane
            float mj = acc;
#pragma unroll
            for (int off = 1; off < 16; off <<= 1)
                mj = fmaxf(mj, __shfl_xor(mj, off, 64));
            ls += me * LN2 + __logf(mj);
            float an = acc * (1.0f / mj);
#pragma unroll
            for (int r = 0; r < 4; ++r)
                ap[r] = __shfl(an, q * 4 + r, 16);
        }

        float part = 0.f;
#pragma unroll
        for (int r = 0; r < 4; ++r)
            part += ap[r] * __expf(trans[STOP_ID * K + 4 * q + r]);
        part += __shfl_xor(part, 16, 64);
        part += __shfl_xor(part, 32, 64);
        if (lane == 0) {
            float gold = Gl[0] + Gl[1] + Gl[2] + Gl[3]
                       + Gl[4] + Gl[5] + Gl[6] + Gl[7];
            res[b] = ls + __logf(part) - gold;
        }
    }
}

// ---------------------------------------------------------------------------
// K2: one block reduces 1024 per-sequence (fwd - gold) values, publishes mean.
// ---------------------------------------------------------------------------
__global__ __launch_bounds__(256) void crf_final(
    const float* __restrict__ res, float* __restrict__ out)
{
    int t = threadIdx.x;
    float v = 0.f;
#pragma unroll
    for (int k2 = 0; k2 < 4; ++k2) v += res[t + 256 * k2];
#pragma unroll
    for (int off = 32; off; off >>= 1) v += __shfl_xor(v, off, 64);
    __shared__ float red[4];
    if ((t & 63) == 0) red[t >> 6] = v;
    __syncthreads();
    if (t == 0) out[0] = (red[0] + red[1] + red[2] + red[3]) * (1.0f / Bn);
}

extern "C" void kernel_launch(void* const* d_in, const int* in_sizes, int n_in,
                              void* d_out, int out_size, void* d_ws, size_t ws_size,
                              hipStream_t stream)
{
    const float* h     = (const float*)d_in[0];
    const int*   y     = (const int*)d_in[1];
    const float* trans = (const float*)d_in[3];
    float* out = (float*)d_out;
    float* res = (float*)d_ws;          // 1024 floats

    // CONTROLLED MEASUREMENT: N=4 launches of the byte-identical R8 kernel
    // (N=2 measured 124.1 us). T4 - T2 = 2*(X+g) => true per-launch cost,
    // with fill/restore/graph overhead cancelling exactly. Idempotent.
    crf_all<<<Bn, 512, 0, stream>>>(h, y, trans, res);
    crf_all<<<Bn, 512, 0, stream>>>(h, y, trans, res);
    crf_all<<<Bn, 512, 0, stream>>>(h, y, trans, res);
    crf_all<<<Bn, 512, 0, stream>>>(h, y, trans, res);
    crf_final<<<1, 256, 0, stream>>>(res, out);
}

// Round 11
// 111.654 us; speedup vs baseline: 1.5369x; 1.5369x over previous
//
#include <hip/hip_runtime.h>
#include <hip/hip_bf16.h>

#define K 16
#define Bn 1024
#define Tn 512
#define START_ID 14
#define STOP_ID 15
#define LN2 0.69314718055994530942f
#define NCH 16         // chunks per sequence
#define CL 32          // chunk length; wave w handles chunks 2w, 2w+1

typedef float f32x4 __attribute__((ext_vector_type(4)));
typedef short s16x4 __attribute__((ext_vector_type(4)));

// f32x4 -> bf16x4 in 6 VALU (round-half-up +0x8000, hi16 via v_perm_b32)
static __device__ __forceinline__ s16x4 pack_bf16x4(float a, float b, float c, float d) {
    unsigned ua = __float_as_uint(a) + 0x8000u;
    unsigned ub = __float_as_uint(b) + 0x8000u;
    unsigned uc = __float_as_uint(c) + 0x8000u;
    unsigned ud = __float_as_uint(d) + 0x8000u;
    union { unsigned u[2]; s16x4 v; } un;
    un.u[0] = __builtin_amdgcn_perm(ub, ua, 0x07060302);
    un.u[1] = __builtin_amdgcn_perm(ud, uc, 0x07060302);
    return un.v;
}

// ---------------------------------------------------------------------------
// R9's verified structure (dual-32 leaf chains + lane-local combine) at the
// CORRECT occupancy: __launch_bounds__(512,8) -> 4 blocks/CU -> ONE block
// generation (R9 ran 2 at (512,4): measured 2x the per-gen cost). Register
// diet to fit the 64-VGPR cap without spill: prefetch depth 4 (sub-block =
// 4 steps), exp computed in place over the h buffer, single base pointer.
// Rescale every 4 steps: pend probed at r==1, applied exactly (2^-pend) at
// the next sub-block's B-pack. Gold fused, 1 gather/thread (tid == t).
// ---------------------------------------------------------------------------
__global__ __launch_bounds__(512, 8) void crf_all(
    const float* __restrict__ h, const int* __restrict__ y,
    const float* __restrict__ trans, float* __restrict__ res)
{
    __shared__ float Pl[NCH][16][20];   // [chunk][row][col], stride 20
    __shared__ float El[NCH][16];       // per-column exponent sums
    __shared__ float Gl[8];

    int tid = threadIdx.x, lane = tid & 63, w = tid >> 6, b = blockIdx.x;
    int s = lane & 15, q = lane >> 4;

    const int* yseq = y + (size_t)b * Tn;
    int yt = yseq[tid];                 // tid == t
    unsigned long long bal = __ballot(yt != 0);
    int nv0 = __popcll(bal & 0xffffffffull);   // chunk 2w   (t = 64w+0..31)
    int nv1 = __popcll(bal >> 32);             // chunk 2w+1 (t = 64w+32..63)

    // ---- gold: one (b,t) per thread; pre-warms L2 with the chain's lines --
    const float* hseq = h + (size_t)b * Tn * K;
    float g = 0.f;
    if (yt != 0) {
        int yp = (tid == 0) ? START_ID : yseq[tid - 1];
        g = hseq[(size_t)tid * K + yt] + trans[yt * K + yp];
        bool last = (tid == Tn - 1) || (yseq[tid + 1] == 0);
        if (last) g += trans[STOP_ID * K + yt];
    }
#pragma unroll
    for (int off = 32; off; off >>= 1) g += __shfl_xor(g, off, 64);
    if (lane == 0) Gl[w] = g;

    // ---- E row for this lane (exp(-10000) -> 0 exactly) ----
    float E0[4];
#pragma unroll
    for (int r = 0; r < 4; ++r)
        E0[r] = __expf(trans[s * K + 4 * q + r]);

    f32x4 P0, P1;
    s16x4 bf0, bf1;
#pragma unroll
    for (int r = 0; r < 4; ++r) {
        float iv = (4 * q + r == s) ? 1.0f : 0.0f;
        P0[r] = iv; P1[r] = iv;
        short bv = (4 * q + r == s) ? (short)0x3F80 : (short)0;
        ((short*)&bf0)[r] = bv; ((short*)&bf1)[r] = bv;
    }

    int es0 = 0, pd0 = 0, es1 = 0, pd1 = 0;
    const float* hc0 = hseq + (size_t)(w * 64) * K + s;   // chain1 at +CL*K

    float h0c[4], h1c[4], h0n[4], h1n[4];
#pragma unroll
    for (int r = 0; r < 4; ++r) {
        h0c[r] = hc0[r * K];
        h1c[r] = hc0[(CL + r) * K];
    }

    int nvmax = nv0 > nv1 ? nv0 : nv1;
    for (int sb = 0; sb < CL / 4; ++sb) {
        int base = sb * 4;
        if (base >= nvmax) break;              // wave-uniform
        int n0 = nv0 - base, n1 = nv1 - base;

        es0 += pd0;
        float sc0 = __uint_as_float((unsigned)(127 - pd0) << 23);  // 2^-pd0
        pd0 = 0;
        es1 += pd1;
        float sc1 = __uint_as_float((unsigned)(127 - pd1) << 23);
        pd1 = 0;
        P0[0] *= sc0; P0[1] *= sc0; P0[2] *= sc0; P0[3] *= sc0;
        P1[0] *= sc1; P1[1] *= sc1; P1[2] *= sc1; P1[3] *= sc1;
        bf0 = pack_bf16x4(P0[0], P0[1], P0[2], P0[3]);
        bf1 = pack_bf16x4(P1[0], P1[1], P1[2], P1[3]);

        // exp in place (saves 8 VGPRs vs separate es[] buffers)
#pragma unroll
        for (int r = 0; r < 4; ++r) {
            h0c[r] = __expf(h0c[r]);
            h1c[r] = __expf(h1c[r]);
        }
        // depth-4 prefetch (clamped inside each chunk)
#pragma unroll
        for (int r = 0; r < 4; ++r) {
            int tt = base + 4 + r; tt = tt > CL - 1 ? CL - 1 : tt;
            h0n[r] = hc0[tt * K];
            h1n[r] = hc0[(CL + tt) * K];
        }
#pragma unroll
        for (int r = 0; r < 4; ++r) {
            if (r < n0) {                      // wave-uniform
                s16x4 af = pack_bf16x4(h0c[r] * E0[0], h0c[r] * E0[1],
                                       h0c[r] * E0[2], h0c[r] * E0[3]);
                f32x4 C = __builtin_amdgcn_mfma_f32_16x16x16bf16_1k(
                    af, bf0, (f32x4){0.f, 0.f, 0.f, 0.f}, 0, 0, 0);
                if (r == 1) {
                    float m4 = fmaxf(fmaxf(C[0], C[1]), fmaxf(C[2], C[3]));
                    m4 = fmaxf(m4, __shfl_xor(m4, 16, 64));
                    m4 = fmaxf(m4, __shfl_xor(m4, 32, 64));
                    int e = (int)(__float_as_uint(m4) >> 23) - 127;
                    pd0 = e < -126 ? -126 : (e > 126 ? 126 : e);
                }
                bf0 = pack_bf16x4(C[0], C[1], C[2], C[3]);
                P0 = C;
            }
            if (r < n1) {                      // wave-uniform
                s16x4 af = pack_bf16x4(h1c[r] * E0[0], h1c[r] * E0[1],
                                       h1c[r] * E0[2], h1c[r] * E0[3]);
                f32x4 C = __builtin_amdgcn_mfma_f32_16x16x16bf16_1k(
                    af, bf1, (f32x4){0.f, 0.f, 0.f, 0.f}, 0, 0, 0);
                if (r == 1) {
                    float m4 = fmaxf(fmaxf(C[0], C[1]), fmaxf(C[2], C[3]));
                    m4 = fmaxf(m4, __shfl_xor(m4, 16, 64));
                    m4 = fmaxf(m4, __shfl_xor(m4, 32, 64));
                    int e = (int)(__float_as_uint(m4) >> 23) - 127;
                    pd1 = e < -126 ? -126 : (e > 126 ? 126 : e);
                }
                bf1 = pack_bf16x4(C[0], C[1], C[2], C[3]);
                P1 = C;
            }
        }
#pragma unroll
        for (int r = 0; r < 4; ++r) { h0c[r] = h0n[r]; h1c[r] = h1n[r]; }
    }

    // publish both chunk results (column s, rows 4q+r)
#pragma unroll
    for (int r = 0; r < 4; ++r) {
        Pl[2 * w][4 * q + r][s]     = P0[r];
        Pl[2 * w + 1][4 * q + r][s] = P1[r];
    }
    if (q == 0) {
        El[2 * w][s]     = (float)es0;
        El[2 * w + 1][s] = (float)es1;
    }
    __syncthreads();

    // ---- combine, lane-local (R9-verified): lanes 0..15, lane j owns row j
    //      and a replicated alpha[16]; per chunk 16 parallel bpermutes ----
    if (tid < 16) {
        int j = tid;
        float al[16];
#pragma unroll
        for (int k2 = 0; k2 < 16; ++k2) al[k2] = (k2 == START_ID) ? 1.f : 0.f;
        float ls = 0.f;

        for (int cc = 0; cc < NCH; ++cc) {
            f32x4 ev0 = *(const f32x4*)&El[cc][0];
            f32x4 ev1 = *(const f32x4*)&El[cc][4];
            f32x4 ev2 = *(const f32x4*)&El[cc][8];
            f32x4 ev3 = *(const f32x4*)&El[cc][12];
            float me = fmaxf(fmaxf(fmaxf(ev0[0], ev0[1]), fmaxf(ev0[2], ev0[3])),
                       fmaxf(fmaxf(fmaxf(ev1[0], ev1[1]), fmaxf(ev1[2], ev1[3])),
                       fmaxf(fmaxf(fmaxf(ev2[0], ev2[1]), fmaxf(ev2[2], ev2[3])),
                             fmaxf(fmaxf(ev3[0], ev3[1]), fmaxf(ev3[2], ev3[3])))));
            int ime = (int)me;
            f32x4 pr0 = *(const f32x4*)&Pl[cc][j][0];
            f32x4 pr1 = *(const f32x4*)&Pl[cc][j][4];
            f32x4 pr2 = *(const f32x4*)&Pl[cc][j][8];
            f32x4 pr3 = *(const f32x4*)&Pl[cc][j][12];
            float acc = 0.f;
#pragma unroll
            for (int r = 0; r < 4; ++r) {
                acc += pr0[r] * ldexpf(al[r],      (int)ev0[r] - ime);
                acc += pr1[r] * ldexpf(al[4 + r],  (int)ev1[r] - ime);
                acc += pr2[r] * ldexpf(al[8 + r],  (int)ev2[r] - ime);
                acc += pr3[r] * ldexpf(al[12 + r], (int)ev3[r] - ime);
            }
            float aln[16];
#pragma unroll
            for (int k2 = 0; k2 < 16; ++k2)
                aln[k2] = __shfl(acc, k2, 16);   // 16 parallel bpermutes
            float mx = aln[0];
#pragma unroll
            for (int k2 = 1; k2 < 16; ++k2) mx = fmaxf(mx, aln[k2]);
            float inv = 1.0f / mx;
#pragma unroll
            for (int k2 = 0; k2 < 16; ++k2) al[k2] = aln[k2] * inv;
            ls += me * LN2 + __logf(mx);
        }

        float part = 0.f;
#pragma unroll
        for (int k2 = 0; k2 < 16; ++k2)
            part += al[k2] * __expf(trans[STOP_ID * K + k2]);
        if (j == 0) {
            float gold = Gl[0] + Gl[1] + Gl[2] + Gl[3]
                       + Gl[4] + Gl[5] + Gl[6] + Gl[7];
            res[b] = ls + __logf(part) - gold;
        }
    }
}

// ---------------------------------------------------------------------------
// K2: one block reduces 1024 per-sequence (fwd - gold) values, publishes mean.
// ---------------------------------------------------------------------------
__global__ __launch_bounds__(256) void crf_final(
    const float* __restrict__ res, float* __restrict__ out)
{
    int t = threadIdx.x;
    float v = 0.f;
#pragma unroll
    for (int k2 = 0; k2 < 4; ++k2) v += res[t + 256 * k2];
#pragma unroll
    for (int off = 32; off; off >>= 1) v += __shfl_xor(v, off, 64);
    __shared__ float red[4];
    if ((t & 63) == 0) red[t >> 6] = v;
    __syncthreads();
    if (t == 0) out[0] = (red[0] + red[1] + red[2] + red[3]) * (1.0f / Bn);
}

extern "C" void kernel_launch(void* const* d_in, const int* in_sizes, int n_in,
                              void* d_out, int out_size, void* d_ws, size_t ws_size,
                              hipStream_t stream)
{
    const float* h     = (const float*)d_in[0];
    const int*   y     = (const int*)d_in[1];
    const float* trans = (const float*)d_in[3];
    float* out = (float*)d_out;
    float* res = (float*)d_ws;          // 1024 floats

    crf_all<<<Bn, 512, 0, stream>>>(h, y, trans, res);
    crf_final<<<1, 256, 0, stream>>>(res, out);
}

// Round 12
// 99.664 us; speedup vs baseline: 1.7218x; 1.1203x over previous
//
#include <hip/hip_runtime.h>
#include <hip/hip_bf16.h>

#define K 16
#define Bn 1024
#define Tn 512
#define START_ID 14
#define STOP_ID 15
#define LN2 0.69314718055994530942f
#define NCH 8          // chunks per sequence (one block = one sequence)
#define CL 64          // chunk length == wave size; threadIdx.x == t

typedef float f32x4 __attribute__((ext_vector_type(4)));
typedef short s16x4 __attribute__((ext_vector_type(4)));

// f32x4 -> bf16x4 in 6 VALU (round-half-up +0x8000, hi16 via v_perm_b32)
static __device__ __forceinline__ s16x4 pack_bf16x4(float a, float b, float c, float d) {
    unsigned ua = __float_as_uint(a) + 0x8000u;
    unsigned ub = __float_as_uint(b) + 0x8000u;
    unsigned uc = __float_as_uint(c) + 0x8000u;
    unsigned ud = __float_as_uint(d) + 0x8000u;
    union { unsigned u[2]; s16x4 v; } un;
    un.u[0] = __builtin_amdgcn_perm(ub, ua, 0x07060302);
    un.u[1] = __builtin_amdgcn_perm(ud, uc, 0x07060302);
    return un.v;
}

// ---------------------------------------------------------------------------
// BYTE-IDENTICAL to the R8/R10 kernel, whose per-launch cost was pinned by
// the R10 controlled N=4 measurement: X+g = 23.74 us. Single launch.
// Structure (best of 5 structural variants tested): one block (8 waves) per
// sequence; wave c evolves chunk c (64 steps) of the 16x16 linear-space
// transfer matrix P <- (D_t E) P, one mfma/step, exp(h) folded into the
// A-operand; per-column pow2 rescale every 8 steps (pend at r==3, applied
// exactly at the next sub-block's B-pack); gold fused (1 gather/thread);
// P/esum/gold -> LDS -> wave 0 combines -> res[b] = fwd_b - gold_b.
// Dual-chain (R9/R11) and CL=128 (R7) variants measured WORSE (34/28 us).
// ---------------------------------------------------------------------------
__global__ __launch_bounds__(512, 8) void crf_all(
    const float* __restrict__ h, const int* __restrict__ y,
    const float* __restrict__ trans, float* __restrict__ res)
{
    __shared__ float Pl[NCH][16][16];   // [chunk][row][col]
    __shared__ float El[NCH][16];       // per-column exponent sums
    __shared__ float Gl[NCH];           // per-wave gold partials

    int tid  = threadIdx.x;             // == t
    int lane = tid & 63;
    int c    = tid >> 6;                // wave id == chunk id
    int b    = blockIdx.x;
    int s = lane & 15, q = lane >> 4;

    const int* yseq = y + (size_t)b * Tn;
    int yt = yseq[tid];
    unsigned long long bal = __ballot(yt != 0);
    int nv = __popcll(bal);             // valid steps in this chunk (prefix)

    // ---- gold: one (b,t) per thread; also pre-warms L2 ----
    const float* hseq = h + ((size_t)b * Tn) * K;
    float g = 0.f;
    if (yt != 0) {
        int yp = (tid == 0) ? START_ID : yseq[tid - 1];
        g = hseq[(size_t)tid * K + yt] + trans[yt * K + yp];
        bool last = (tid == Tn - 1) || (yseq[tid + 1] == 0);
        if (last) g += trans[STOP_ID * K + yt];
    }
#pragma unroll
    for (int off = 32; off; off >>= 1) g += __shfl_xor(g, off, 64);
    if (lane == 0) Gl[c] = g;

    // ---- chain ----
    float E0[4];
#pragma unroll
    for (int r = 0; r < 4; ++r)
        E0[r] = __expf(trans[s * K + 4 * q + r]);   // exp(-10000) -> 0

    f32x4 P;
    s16x4 bfrag;
#pragma unroll
    for (int r = 0; r < 4; ++r) {
        P[r] = (4 * q + r == s) ? 1.0f : 0.0f;
        ((short*)&bfrag)[r] = (4 * q + r == s) ? (short)0x3F80 : (short)0;
    }

    int esum = 0, pend = 0;
    const float* hcs = hseq + (size_t)c * CL * K + s;

    float hcur[8], hnxt[8];
#pragma unroll
    for (int r = 0; r < 8; ++r) hcur[r] = hcs[(size_t)r * K];

    for (int sb = 0; sb < CL / 8; ++sb) {
        int base = sb * 8;
        if (base >= nv) break;                 // wave-uniform
        int n = nv - base; if (n > 8) n = 8;

        esum += pend;
        float sc = __uint_as_float((unsigned)(127 - pend) << 23); // exact 2^-pend
        pend = 0;
        P[0] *= sc; P[1] *= sc; P[2] *= sc; P[3] *= sc;
        bfrag = pack_bf16x4(P[0], P[1], P[2], P[3]);

        float es[8];
#pragma unroll
        for (int r = 0; r < 8; ++r) es[r] = __expf(hcur[r]);
#pragma unroll
        for (int r = 0; r < 8; ++r) {          // depth-1 prefetch (clamped)
            int tt = base + 8 + r; tt = tt > CL - 1 ? CL - 1 : tt;
            hnxt[r] = hcs[(size_t)tt * K];
        }
#pragma unroll
        for (int r = 0; r < 8; ++r) {
            if (r >= n) break;                 // wave-uniform
            s16x4 afrag = pack_bf16x4(es[r] * E0[0], es[r] * E0[1],
                                      es[r] * E0[2], es[r] * E0[3]);
            f32x4 C = __builtin_amdgcn_mfma_f32_16x16x16bf16_1k(
                afrag, bfrag, (f32x4){0.f, 0.f, 0.f, 0.f}, 0, 0, 0);
            if (r == 3) {                      // per-column max -> pending 2^e
                float m4 = fmaxf(fmaxf(C[0], C[1]), fmaxf(C[2], C[3]));
                m4 = fmaxf(m4, __shfl_xor(m4, 16, 64));
                m4 = fmaxf(m4, __shfl_xor(m4, 32, 64));
                int e = (int)(__float_as_uint(m4) >> 23) - 127;
                pend = e < -126 ? -126 : (e > 126 ? 126 : e);
            }
            bfrag = pack_bf16x4(C[0], C[1], C[2], C[3]);
            P = C;
        }
#pragma unroll
        for (int r = 0; r < 8; ++r) hcur[r] = hnxt[r];
    }

    // publish chunk result (column s, rows 4q+r)
#pragma unroll
    for (int r = 0; r < 4; ++r)
        Pl[c][4 * q + r][s] = P[r];
    if (q == 0) El[c][s] = (float)esum;
    __syncthreads();

    // ---- combine (wave 0): alpha = e_START; alpha' = P~ * ldexp(w) ----
    if (c == 0) {
        int j = s;
        float ap[4];
#pragma unroll
        for (int r = 0; r < 4; ++r) ap[r] = (4 * q + r == START_ID) ? 1.0f : 0.0f;
        float ls = 0.f;

#pragma unroll
        for (int cc = 0; cc < NCH; ++cc) {
            f32x4 Pr  = *(const f32x4*)&Pl[cc][j][4 * q];
            f32x4 Erv = *(const f32x4*)&El[cc][4 * q];
            float me = fmaxf(fmaxf(Erv[0], Erv[1]), fmaxf(Erv[2], Erv[3]));
            me = fmaxf(me, __shfl_xor(me, 16, 64));
            me = fmaxf(me, __shfl_xor(me, 32, 64));
            float w0 = ldexpf(ap[0], (int)(Erv[0] - me));
            float w1 = ldexpf(ap[1], (int)(Erv[1] - me));
            float w2 = ldexpf(ap[2], (int)(Erv[2] - me));
            float w3 = ldexpf(ap[3], (int)(Erv[3] - me));
            float acc = Pr[0]*w0 + Pr[1]*w1 + Pr[2]*w2 + Pr[3]*w3;
            acc += __shfl_xor(acc, 16, 64);
            acc += __shfl_xor(acc, 32, 64);    // alpha'[j] at every lane
            float mj = acc;
#pragma unroll
            for (int off = 1; off < 16; off <<= 1)
                mj = fmaxf(mj, __shfl_xor(mj, off, 64));
            ls += me * LN2 + __logf(mj);
            float an = acc * (1.0f / mj);
#pragma unroll
            for (int r = 0; r < 4; ++r)
                ap[r] = __shfl(an, q * 4 + r, 16);
        }

        float part = 0.f;
#pragma unroll
        for (int r = 0; r < 4; ++r)
            part += ap[r] * __expf(trans[STOP_ID * K + 4 * q + r]);
        part += __shfl_xor(part, 16, 64);
        part += __shfl_xor(part, 32, 64);
        if (lane == 0) {
            float gold = Gl[0] + Gl[1] + Gl[2] + Gl[3]
                       + Gl[4] + Gl[5] + Gl[6] + Gl[7];
            res[b] = ls + __logf(part) - gold;
        }
    }
}

// ---------------------------------------------------------------------------
// K2: one block reduces 1024 per-sequence (fwd - gold) values, publishes mean.
// ---------------------------------------------------------------------------
__global__ __launch_bounds__(256) void crf_final(
    const float* __restrict__ res, float* __restrict__ out)
{
    int t = threadIdx.x;
    float v = 0.f;
#pragma unroll
    for (int k2 = 0; k2 < 4; ++k2) v += res[t + 256 * k2];
#pragma unroll
    for (int off = 32; off; off >>= 1) v += __shfl_xor(v, off, 64);
    __shared__ float red[4];
    if ((t & 63) == 0) red[t >> 6] = v;
    __syncthreads();
    if (t == 0) out[0] = (red[0] + red[1] + red[2] + red[3]) * (1.0f / Bn);
}

extern "C" void kernel_launch(void* const* d_in, const int* in_sizes, int n_in,
                              void* d_out, int out_size, void* d_ws, size_t ws_size,
                              hipStream_t stream)
{
    const float* h     = (const float*)d_in[0];
    const int*   y     = (const int*)d_in[1];
    const float* trans = (const float*)d_in[3];
    float* out = (float*)d_out;
    float* res = (float*)d_ws;          // 1024 floats

    crf_all<<<Bn, 512, 0, stream>>>(h, y, trans, res);
    crf_final<<<1, 256, 0, stream>>>(res, out);
}